// Round 1
// baseline (253.392 us; speedup 1.0000x reference)
//
#include <hip/hip_runtime.h>
#include <stdint.h>

// Round 1: f16 MFMA flash-attention implementation.
// inputs: d_in[0]=x fp32 [4,64,64,256], d_in[1..3]=Wv,Wk,Wq fp32 [256,256], d_in[4]=gamma fp32 [1]
// out: fp32 [4,64,64,256]
//
// ws layout (bytes):
//   VOFF: v  f16, tile-swizzled [256 tiles][64 rows][256 c]   8 MB
//   KOFF: k  f16, same layout                                  8 MB
//   QOFF: qT f16, per batch [64 tiles][256 c][64 n] swizzled   8 MB
//   WOFF: W^T f16 [3][256 c][256 k]                            384 KB
// total ~24.4 MB (assumes ws_size >= 26 MB)

typedef _Float16 f16;
typedef __attribute__((ext_vector_type(8))) _Float16 f16x8;
typedef __attribute__((ext_vector_type(4))) float f32x4;
typedef __attribute__((ext_vector_type(4))) unsigned int u32x4;

#define MFMA16(a, b, c) __builtin_amdgcn_mfma_f32_16x16x32_f16((a), (b), (c), 0, 0, 0)

constexpr size_t VOFF = 0;
constexpr size_t KOFF = (size_t)8 << 20;
constexpr size_t QOFF = (size_t)16 << 20;
constexpr size_t WOFF = (size_t)24 << 20;

// ---------------------------------------------------------------- kernel 1
// WT[p][c][k] = (f16) W_p[k][c]
__global__ __launch_bounds__(256) void wt_kernel(const float* __restrict__ wv,
                                                 const float* __restrict__ wk,
                                                 const float* __restrict__ wq,
                                                 f16* __restrict__ wt) {
  int idx = blockIdx.x * 256 + threadIdx.x;  // 0 .. 3*65536-1
  int p = idx >> 16;
  int rem = idx & 65535;
  int c = rem >> 8, k = rem & 255;
  const float* w = (p == 0) ? wv : (p == 1) ? wk : wq;
  wt[idx] = (f16)w[k * 256 + c];
}

// ---------------------------------------------------------------- kernel 2
// projections: v,k,q = x @ W{v,k,q}. One WG = 64 rows, 4 waves x 16 rows.
__global__ __launch_bounds__(256) void proj_kernel(const float* __restrict__ x,
                                                   uint8_t* __restrict__ ws) {
  __shared__ __align__(16) uint8_t xt[32768];  // x tile f16 [64][256], row-swizzled
  __shared__ __align__(16) uint8_t ot[32768];  // out tile f16 [64][256], row-swizzled

  const int tid = threadIdx.x;
  const int blk = blockIdx.x;  // global row-block, rows [blk*64, +64)
  const int lane = tid & 63, wid = tid >> 6;
  const int l15 = lane & 15, g = lane >> 4;

  // ---- stage x tile (fp32 -> f16, swizzled) ----
  {
    int r = tid >> 2, cb = tid & 3;
    const float* src = x + (size_t)(blk * 64 + r) * 256 + cb * 64;
    int sw = (r & 7) << 4;
#pragma unroll
    for (int jj = 0; jj < 8; ++jj) {
      float4 f0 = *(const float4*)(src + jj * 8);
      float4 f1 = *(const float4*)(src + jj * 8 + 4);
      f16x8 h;
      h[0] = (f16)f0.x; h[1] = (f16)f0.y; h[2] = (f16)f0.z; h[3] = (f16)f0.w;
      h[4] = (f16)f1.x; h[5] = (f16)f1.y; h[6] = (f16)f1.z; h[7] = (f16)f1.w;
      int addr = r * 512 + ((cb * 128 + jj * 16) ^ sw);
      *(f16x8*)(xt + addr) = h;
    }
  }
  __syncthreads();

  const f16* wtp = (const f16*)(ws + WOFF);
  const int arow = wid * 16 + l15;
  const int asw = (arow & 7) << 4;

  for (int p = 0; p < 3; ++p) {
    f32x4 o[16];
#pragma unroll
    for (int t = 0; t < 16; ++t) o[t] = (f32x4){0.f, 0.f, 0.f, 0.f};
    const f16* wp = wtp + p * 65536;

#pragma unroll
    for (int kc = 0; kc < 8; ++kc) {
      f16x8 a = *(const f16x8*)(xt + arow * 512 + ((kc * 64 + g * 16) ^ asw));
#pragma unroll
      for (int t = 0; t < 16; ++t) {
        int col = t * 16 + l15;
        f16x8 b = *(const f16x8*)(wp + col * 256 + kc * 32 + g * 8);
        o[t] = MFMA16(a, b, o[t]);
      }
    }

    __syncthreads();
    // frags -> ot (f16, row-swizzled [64][256])
#pragma unroll
    for (int t = 0; t < 16; ++t) {
#pragma unroll
      for (int r = 0; r < 4; ++r) {
        int prow = wid * 16 + g * 4 + r;
        int pcol = t * 16 + l15;
        int addr = prow * 512 + ((pcol * 2) ^ ((prow & 7) << 4));
        *(f16*)(ot + addr) = (f16)o[t][r];
      }
    }
    __syncthreads();

    if (p < 2) {
      // v/k: LDS tile layout == global tile layout -> linear copy
      uint8_t* dst = ws + (p == 0 ? VOFF : KOFF) + (size_t)blk * 32768;
#pragma unroll
      for (int jj = 0; jj < 8; ++jj) {
        u32x4 d = *(const u32x4*)(ot + jj * 4096 + tid * 16);
        *(u32x4*)(dst + jj * 4096 + tid * 16) = d;
      }
    } else {
      // qT: thread = column c; write [c][64 n] with n-chunk swizzle (c&3)<<4
      int c = tid;
      int b2 = blk >> 6, kt2 = blk & 63;
      uint8_t* dst = ws + QOFF + (size_t)b2 * 2097152 + (size_t)kt2 * 32768 + c * 128;
#pragma unroll
      for (int jj = 0; jj < 8; ++jj) {
        u32x4 d;
#pragma unroll
        for (int q = 0; q < 4; ++q) {
          int r0 = jj * 8 + q * 2, r1 = r0 + 1;
          uint32_t lo = *(const uint16_t*)(ot + r0 * 512 + ((c * 2) ^ ((r0 & 7) << 4)));
          uint32_t hi = *(const uint16_t*)(ot + r1 * 512 + ((c * 2) ^ ((r1 & 7) << 4)));
          d[q] = lo | (hi << 16);
        }
        *(u32x4*)(dst + ((jj * 16) ^ ((c & 3) << 4))) = d;
      }
    }
    __syncthreads();
  }
}

// ---------------------------------------------------------------- kernel 3
// flash attention: S = V K^T * gamma, beta = softmax(S), O = beta Q, out = O + x
// 256 WGs: (batch, 64-row block). 4 waves x 16 rows. KV tile = 64 keys.
// dynamic LDS: K dbuf 2*32K | Q dbuf 2*32K | P 4*2K  = 139264 B
__global__ __launch_bounds__(256, 1) void flash_kernel(const float* __restrict__ x,
                                                       const float* __restrict__ gptr,
                                                       float* __restrict__ out,
                                                       const uint8_t* __restrict__ ws) {
  extern __shared__ __align__(16) uint8_t lds[];
  const int tid = threadIdx.x, lane = tid & 63, wid = tid >> 6;
  const int l15 = lane & 15, g = lane >> 4;

  // XCD-aware swizzle: keep each batch's K/Q resident in 2 XCDs' L2
  int blk = blockIdx.x;
  int swz = (blk & 7) * 32 + (blk >> 3);
  int b = swz >> 6, rb = swz & 63;

  // ---- V fragments (held in registers for the whole kernel) ----
  f16x8 vf[8];
  {
    int r = wid * 16 + l15;
    const uint8_t* vt = ws + VOFF + (size_t)(b * 64 + rb) * 32768 + r * 512;
    int sw = (r & 7) << 4;
#pragma unroll
    for (int cb = 0; cb < 8; ++cb)
      vf[cb] = *(const f16x8*)(vt + ((cb * 64 + g * 16) ^ sw));
  }

  const float gl2 = gptr[0] * 1.44269504088896f;  // gamma * log2(e)

  f32x4 o[16];
#pragma unroll
  for (int t = 0; t < 16; ++t) o[t] = (f32x4){0.f, 0.f, 0.f, 0.f};
  float m[4] = {-1e30f, -1e30f, -1e30f, -1e30f};
  float l[4] = {0.f, 0.f, 0.f, 0.f};

  uint8_t* pbase = lds + 131072 + wid * 2048;  // per-wave P [16][64] f16, row-swizzled
  const uint8_t* ktile0 = ws + KOFF + (size_t)(b * 64) * 32768;
  const uint8_t* qtile0 = ws + QOFF + (size_t)b * 2097152;

  u32x4 stk[8], stq[8];
  // prologue: stage tile 0
#pragma unroll
  for (int i = 0; i < 8; ++i) {
    stk[i] = *(const u32x4*)(ktile0 + i * 4096 + tid * 16);
    stq[i] = *(const u32x4*)(qtile0 + i * 4096 + tid * 16);
  }
#pragma unroll
  for (int i = 0; i < 8; ++i) {
    *(u32x4*)(lds + i * 4096 + tid * 16) = stk[i];
    *(u32x4*)(lds + 65536 + i * 4096 + tid * 16) = stq[i];
  }
  __syncthreads();

  for (int kt = 0; kt < 64; ++kt) {
    const int cur = kt & 1;
    const bool pre = (kt < 63);
    if (pre) {  // issue next-tile global loads early (overlap with compute)
      const uint8_t* kt1 = ktile0 + (size_t)(kt + 1) * 32768;
      const uint8_t* qt1 = qtile0 + (size_t)(kt + 1) * 32768;
#pragma unroll
      for (int i = 0; i < 8; ++i) {
        stk[i] = *(const u32x4*)(kt1 + i * 4096 + tid * 16);
        stq[i] = *(const u32x4*)(qt1 + i * 4096 + tid * 16);
      }
    }
    const uint8_t* kbuf = lds + cur * 32768;
    const uint8_t* qbuf = lds + 65536 + cur * 32768;

    // ---- scores: S(16x64) = V(16x256) @ K^T ----
    f32x4 s[4];
#pragma unroll
    for (int t = 0; t < 4; ++t) s[t] = (f32x4){0.f, 0.f, 0.f, 0.f};
#pragma unroll
    for (int cb = 0; cb < 8; ++cb) {
#pragma unroll
      for (int t = 0; t < 4; ++t) {
        int key = t * 16 + l15;
        f16x8 kb =
            *(const f16x8*)(kbuf + key * 512 + ((cb * 64 + g * 16) ^ ((key & 7) << 4)));
        s[t] = MFMA16(vf[cb], kb, s[t]);
      }
    }

    // ---- online softmax (rows = (g*4+r), cols spread over 16-lane group) ----
    float rm[4], sc[4], rs[4];
#pragma unroll
    for (int r = 0; r < 4; ++r) {
#pragma unroll
      for (int t = 0; t < 4; ++t) s[t][r] *= gl2;  // into log2 domain (incl. gamma)
      rm[r] = fmaxf(fmaxf(s[0][r], s[1][r]), fmaxf(s[2][r], s[3][r]));
    }
#pragma unroll
    for (int msk = 1; msk < 16; msk <<= 1)
#pragma unroll
      for (int r = 0; r < 4; ++r) rm[r] = fmaxf(rm[r], __shfl_xor(rm[r], msk, 64));

#pragma unroll
    for (int r = 0; r < 4; ++r) {
      float mn = fmaxf(m[r], rm[r]);
      sc[r] = __builtin_amdgcn_exp2f(m[r] - mn);
      m[r] = mn;
      rs[r] = 0.f;
    }
    // P = exp2(s - m) -> per-wave LDS (f16)
#pragma unroll
    for (int t = 0; t < 4; ++t) {
#pragma unroll
      for (int r = 0; r < 4; ++r) {
        float p = __builtin_amdgcn_exp2f(s[t][r] - m[r]);
        rs[r] += p;
        int prow = g * 4 + r, pcol = t * 16 + l15;
        *(f16*)(pbase + prow * 128 + ((pcol * 2) ^ ((prow & 7) << 4))) = (f16)p;
      }
    }
#pragma unroll
    for (int msk = 1; msk < 16; msk <<= 1)
#pragma unroll
      for (int r = 0; r < 4; ++r) rs[r] += __shfl_xor(rs[r], msk, 64);
#pragma unroll
    for (int r = 0; r < 4; ++r) l[r] = l[r] * sc[r] + rs[r];
#pragma unroll
    for (int t = 0; t < 16; ++t)
#pragma unroll
      for (int r = 0; r < 4; ++r) o[t][r] *= sc[r];

    // ---- PV: O(16x256) += P(16x64) @ Q(64x256) ----
    int psw = (l15 & 7) << 4;
    f16x8 pa0 = *(const f16x8*)(pbase + l15 * 128 + ((g * 16) ^ psw));
    f16x8 pa1 = *(const f16x8*)(pbase + l15 * 128 + ((64 + g * 16) ^ psw));
#pragma unroll
    for (int t = 0; t < 16; ++t) {
      int c = t * 16 + l15;
      int csw = (c & 3) << 4;
      f16x8 q0 = *(const f16x8*)(qbuf + c * 128 + ((g * 16) ^ csw));
      f16x8 q1 = *(const f16x8*)(qbuf + c * 128 + ((64 + g * 16) ^ csw));
      o[t] = MFMA16(pa0, q0, o[t]);
      o[t] = MFMA16(pa1, q1, o[t]);
    }

    if (pre) {  // write prefetched tile into the other buffer
      uint8_t* nk = lds + (cur ^ 1) * 32768;
      uint8_t* nq = lds + 65536 + (cur ^ 1) * 32768;
#pragma unroll
      for (int i = 0; i < 8; ++i) {
        *(u32x4*)(nk + i * 4096 + tid * 16) = stk[i];
        *(u32x4*)(nq + i * 4096 + tid * 16) = stq[i];
      }
    }
    __syncthreads();
  }

  // ---- epilogue: out = O / l + x ----
  float inv[4];
#pragma unroll
  for (int r = 0; r < 4; ++r) inv[r] = 1.0f / l[r];
#pragma unroll
  for (int t = 0; t < 16; ++t) {
#pragma unroll
    for (int r = 0; r < 4; ++r) {
      size_t grow = (size_t)b * 4096 + (size_t)rb * 64 + wid * 16 + g * 4 + r;
      size_t idx = grow * 256 + t * 16 + l15;
      out[idx] = o[t][r] * inv[r] + x[idx];
    }
  }
}

// ---------------------------------------------------------------- launch
extern "C" void kernel_launch(void* const* d_in, const int* in_sizes, int n_in,
                              void* d_out, int out_size, void* d_ws, size_t ws_size,
                              hipStream_t stream) {
  (void)in_sizes; (void)n_in; (void)out_size; (void)ws_size;
  const float* x = (const float*)d_in[0];
  const float* wv = (const float*)d_in[1];
  const float* wk = (const float*)d_in[2];
  const float* wq = (const float*)d_in[3];
  const float* gamma = (const float*)d_in[4];
  float* out = (float*)d_out;
  uint8_t* ws = (uint8_t*)d_ws;

  wt_kernel<<<768, 256, 0, stream>>>(wv, wk, wq, (f16*)(ws + WOFF));
  proj_kernel<<<256, 256, 0, stream>>>(x, ws);

  hipFuncSetAttribute((const void*)flash_kernel,
                      hipFuncAttributeMaxDynamicSharedMemorySize, 139264);
  flash_kernel<<<256, 256, 139264, stream>>>(x, gamma, out, ws);
}